// Round 5
// baseline (249.937 us; speedup 1.0000x reference)
//
#include <hip/hip_runtime.h>
#include <math.h>

// ExodusNeuron: per-(b,n) sequential scan over T with spike threshold/reset.
// x: (B=32, T=2048, N=512, 1) fp32; weight: (1,1) fp32; out: (B,T,N,1) fp32.
//
// R4: producer/consumer, bigger tiles, no spike LDS round-trip.
//   R3 (84us) paid serialized load-latency + SBUF-drain latency in every
//   64-step barrier window (33 windows x ~6100cyc; only 5.4 B/cyc/CU vs
//   ~10.3 achievable). Fixes:
//     - TILE=128 (16 windows): amortize fixed latency over 2x bytes.
//     - Consumer stores spikes DIRECTLY to HBM (256B/wave coalesced,
//       store-ack is L2-fast). Producers only prefetch X. SBUF gone.
//     - Producers load float4 (16 lanes x 16B = 256B segments, 4 rows per
//       instruction): 16 dwordx4 per producer per tile, all in flight.
//   Block: 192 threads = 1 consumer wave + 2 producer waves x 64 rows.
//   LDS: XBUF[2][128][64] = 64 KB. One block per CU (grid 256).
//
// Numerics MUST match numpy's fp32 rounding exactly (outputs are 0/1 spikes;
// a flipped spike = absmax 1.0): separate rounded mul/add (no FMA), and
// alpha = correctly-rounded float of exp(double(float(-0.05))).
// fire ? __fsub_rn(va,1.0f) : va is bitwise identical to va - spk.
// R0-R3 all passed with absmax == 0.0 — do not change the arithmetic.

constexpr int B_ = 32;
constexpr int T_ = 2048;
constexpr int N_ = 512;
constexpr int TILE = 128;              // time steps per tile
constexpr int NTILE = T_ / TILE;       // 16 tiles
constexpr int NCHUNK = 64;             // neurons per block
constexpr int NPROD = 2;               // producer waves
constexpr int ROWS_PER_PROD = TILE / NPROD;   // 64 rows each
constexpr int CHUNKS = ROWS_PER_PROD / 4;     // 16 float4-instructions each

__global__ __launch_bounds__(192, 1)
void exodus_pc_kernel(const float* __restrict__ x,
                      const float* __restrict__ wptr,
                      float* __restrict__ out) {
    __shared__ float XBUF[2][TILE][NCHUNK];   // 64 KB, double-buffered input

    const int blk  = blockIdx.x;          // 0..255
    const int b    = blk >> 3;            // 0..31
    const int n0   = (blk & 7) * NCHUNK;  // 0,64,...,448
    const int wave = threadIdx.x >> 6;    // 0..2
    const int lane = threadIdx.x & 63;

    const size_t bbase = (size_t)b * T_ * N_ + (size_t)n0;

    if (wave != 0) {
        // ================= producers: HBM -> LDS only =================
        const int p     = wave - 1;            // 0..1
        const int r0    = p * ROWS_PER_PROD;   // 0 or 64
        const int rlane = lane >> 4;           // 0..3: row within a 4-row group
        const int c4    = (lane & 15) * 4;     // float column within row

        // prologue: stage tile 0
        {
            const float* __restrict__ g =
                x + bbase + (size_t)(r0 + rlane) * N_ + c4;
            float4 r[CHUNKS];
#pragma unroll
            for (int i = 0; i < CHUNKS; ++i)
                r[i] = *(const float4*)(g + (size_t)i * 4 * N_);
#pragma unroll
            for (int i = 0; i < CHUNKS; ++i)
                *(float4*)&XBUF[0][r0 + i * 4 + rlane][c4] = r[i];
        }
        __syncthreads();

        for (int t = 0; t < NTILE; ++t) {
            if (t + 1 < NTILE) {
                const int bb = (t + 1) & 1;
                const float* __restrict__ g =
                    x + bbase + ((size_t)(t + 1) * TILE + r0 + rlane) * N_ + c4;
                float4 r[CHUNKS];
#pragma unroll
                for (int i = 0; i < CHUNKS; ++i)
                    r[i] = *(const float4*)(g + (size_t)i * 4 * N_);
#pragma unroll
                for (int i = 0; i < CHUNKS; ++i)
                    *(float4*)&XBUF[bb][r0 + i * 4 + rlane][c4] = r[i];
            }
            __syncthreads();
        }
    } else {
        // ================= consumer: LDS -> scan -> HBM =================
        const float w = wptr[0];
        const float alpha = (float)exp((double)(-1.0f / 20.0f));
        float vsyn = 0.0f, vmem = 0.0f;
        float* __restrict__ op = out + bbase + lane;

        __syncthreads();   // matches producer prologue barrier

        for (int t = 0; t < NTILE; ++t) {
            const int bb = t & 1;
            float* __restrict__ o = op + (size_t)t * TILE * N_;
#pragma unroll
            for (int c = 0; c < TILE / 32; ++c) {   // 4 chunks of 32 steps
                float xv[32];
#pragma unroll
                for (int j = 0; j < 32; ++j)
                    xv[j] = XBUF[bb][c * 32 + j][lane];
#pragma unroll
                for (int j = 0; j < 32; ++j) {
                    const float i_t = __fmul_rn(xv[j], w);
                    vsyn = __fadd_rn(__fmul_rn(alpha, vsyn), i_t);
                    const float va = __fadd_rn(__fmul_rn(alpha, vmem), vsyn);
                    const bool fire = (va >= 1.0f);
                    o[(size_t)(c * 32 + j) * N_] = fire ? 1.0f : 0.0f;
                    vmem = fire ? __fsub_rn(va, 1.0f) : va;  // == va - spk
                }
            }
            __syncthreads();
        }
    }
}

extern "C" void kernel_launch(void* const* d_in, const int* in_sizes, int n_in,
                              void* d_out, int out_size, void* d_ws, size_t ws_size,
                              hipStream_t stream) {
    const float* x = (const float*)d_in[0];
    const float* w = (const float*)d_in[1];
    float* out = (float*)d_out;

    dim3 grid(256);    // one block (3 waves) per CU; 64 sequences per block
    dim3 block(192);
    hipLaunchKernelGGL(exodus_pc_kernel, grid, block, 0, stream, x, w, out);
}

// Round 6
// 244.952 us; speedup vs baseline: 1.0204x; 1.0204x over previous
//
#include <hip/hip_runtime.h>
#include <math.h>

// ExodusNeuron: per-(b,n) sequential scan over T with spike threshold/reset.
// x: (B=32, T=2048, N=512, 1) fp32; weight: (1,1) fp32; out: (B,T,N,1) fp32.
//
// R5: async global_load_lds staging (producer = pure DMA issuer).
//   R2-R4 all paid a serialized HBM->VGPR->LDS round-trip inside every
//   barrier window (~190 cyc/KB vs ~77 floor). global_load_lds removes the
//   VGPR hop: producer wave issues 128 fire-and-forget row-DMAs for tile
//   t+1 (row = 64 lanes x 4B = 256B, dest wave-uniform base + lane*4 --
//   our [step][neuron] LDS layout matches the HW constraint exactly),
//   while the consumer scans tile t out of the other buffer. The only
//   wait is the compiler's vmcnt(0) before s_barrier: ONE latency
//   exposure per 128-step window, fully overlapped with compute.
//   Block: 128 threads = 1 consumer wave + 1 producer wave; grid 256
//   (one block/CU); XBUF[2][128][64] = 64 KB LDS; no SBUF (consumer
//   stores spikes straight to HBM, 256B/wave coalesced).
//
// Numerics MUST match numpy's fp32 rounding exactly (outputs are 0/1 spikes;
// a flipped spike = absmax 1.0): separate rounded mul/add (no FMA), and
// alpha = correctly-rounded float of exp(double(float(-0.05))).
// fire ? __fsub_rn(va,1.0f) : va is bitwise identical to va - spk.
// R0-R4 all passed with absmax == 0.0 — do not change the arithmetic.

constexpr int B_ = 32;
constexpr int T_ = 2048;
constexpr int N_ = 512;
constexpr int TILE = 128;              // time steps per tile
constexpr int NTILE = T_ / TILE;       // 16 tiles
constexpr int NCHUNK = 64;             // neurons per block

__device__ __forceinline__ void dma_row(const float* g, float* l) {
    // async HBM->LDS, 4 bytes/lane: lane i of the wave loads g[i] into
    // ldsbase + i*4. Increments vmcnt; drained by waitcnt before barrier.
    __builtin_amdgcn_global_load_lds(
        (const __attribute__((address_space(1))) void*)g,
        (__attribute__((address_space(3))) void*)l,
        4, 0, 0);
}

__global__ __launch_bounds__(128, 1)
void exodus_dma_kernel(const float* __restrict__ x,
                       const float* __restrict__ wptr,
                       float* __restrict__ out) {
    __shared__ float XBUF[2][TILE][NCHUNK];   // 64 KB, double-buffered input

    const int blk  = blockIdx.x;          // 0..255
    const int b    = blk >> 3;            // 0..31
    const int n0   = (blk & 7) * NCHUNK;  // 0,64,...,448
    const int wave = threadIdx.x >> 6;    // 0..1
    const int lane = threadIdx.x & 63;

    const size_t bbase = (size_t)b * T_ * N_ + (size_t)n0;

    if (wave == 1) {
        // ============ producer: pure async DMA issuer ============
        const float* __restrict__ gx = x + bbase + lane;

        // prologue: stage tile 0 into buffer 0
        for (int jj = 0; jj < TILE / 16; ++jj) {
            const float* g = gx + (size_t)(jj * 16) * N_;
#pragma unroll
            for (int i = 0; i < 16; ++i)
                dma_row(g + (size_t)i * N_, &XBUF[0][jj * 16 + i][lane]);
        }
        __syncthreads();   // compiler emits s_waitcnt vmcnt(0) first

        for (int t = 0; t < NTILE; ++t) {
            if (t + 1 < NTILE) {
                const int bb = (t + 1) & 1;
                const float* __restrict__ gt =
                    gx + (size_t)(t + 1) * TILE * N_;
                for (int jj = 0; jj < TILE / 16; ++jj) {
                    const float* g = gt + (size_t)(jj * 16) * N_;
#pragma unroll
                    for (int i = 0; i < 16; ++i)
                        dma_row(g + (size_t)i * N_,
                                &XBUF[bb][jj * 16 + i][lane]);
                }
            }
            __syncthreads();
        }
    } else {
        // ============ consumer: LDS -> scan -> HBM ============
        const float w = wptr[0];
        const float alpha = (float)exp((double)(-1.0f / 20.0f));
        float vsyn = 0.0f, vmem = 0.0f;
        float* __restrict__ op = out + bbase + lane;

        __syncthreads();   // matches producer prologue barrier

        for (int t = 0; t < NTILE; ++t) {
            const int bb = t & 1;
            float* __restrict__ o = op + (size_t)t * TILE * N_;
#pragma unroll
            for (int c = 0; c < TILE / 32; ++c) {   // 4 chunks of 32 steps
                float xv[32];
#pragma unroll
                for (int j = 0; j < 32; ++j)
                    xv[j] = XBUF[bb][c * 32 + j][lane];
#pragma unroll
                for (int j = 0; j < 32; ++j) {
                    const float i_t = __fmul_rn(xv[j], w);
                    vsyn = __fadd_rn(__fmul_rn(alpha, vsyn), i_t);
                    const float va = __fadd_rn(__fmul_rn(alpha, vmem), vsyn);
                    const bool fire = (va >= 1.0f);
                    o[(size_t)(c * 32 + j) * N_] = fire ? 1.0f : 0.0f;
                    vmem = fire ? __fsub_rn(va, 1.0f) : va;  // == va - spk
                }
            }
            __syncthreads();
        }
    }
}

extern "C" void kernel_launch(void* const* d_in, const int* in_sizes, int n_in,
                              void* d_out, int out_size, void* d_ws, size_t ws_size,
                              hipStream_t stream) {
    const float* x = (const float*)d_in[0];
    const float* w = (const float*)d_in[1];
    float* out = (float*)d_out;

    dim3 grid(256);    // one block (2 waves) per CU; 64 sequences per block
    dim3 block(128);
    hipLaunchKernelGGL(exodus_dma_kernel, grid, block, 0, stream, x, w, out);
}

// Round 7
// 239.707 us; speedup vs baseline: 1.0427x; 1.0219x over previous
//
#include <hip/hip_runtime.h>
#include <math.h>

// ExodusNeuron: per-(b,n) sequential scan over T with spike threshold/reset.
// x: (B=32, T=2048, N=512, 1) fp32; weight: (1,1) fp32; out: (B,T,N,1) fp32.
//
// R6: R3's structure (the best so far, 84us) with 2x the producer waves.
//   Evidence across R0-R5: per-wave outstanding-vmem is HW-capped (~8-15;
//   R1's 64-deep register pipeline == 8-deep, DMA == loads), so aggregate
//   HBM BW scales with the NUMBER of waves issuing vmem, not per-wave
//   pipeline depth. R3(4 producer waves)=84us beat R4(2)=95us beat
//   R5(1)=115us. This round: 8 producer waves (block=576), everything
//   else identical to R3 — a clean A/B on the wave-count theory.
//   Per block: wave 0 = consumer (LDS-only sequential scan, 64 neurons),
//   waves 1-8 = producers, each staging 8 rows/window (batched reg loads
//   -> ds_writes) and draining 8 spike rows (ds_reads -> stores).
//   Tiles: 64 steps x 64 neurons, double-buffered. LDS = 64 KB exactly.
//
// Numerics MUST match numpy's fp32 rounding exactly (outputs are 0/1 spikes;
// a flipped spike = absmax 1.0): separate rounded mul/add (no FMA), and
// alpha = correctly-rounded float of exp(double(float(-0.05))).
// fire ? __fsub_rn(va,1.0f) : va is bitwise identical to va - spk.
// R0-R5 all passed with absmax == 0.0 — do not change the arithmetic.

constexpr int B_ = 32;
constexpr int T_ = 2048;
constexpr int N_ = 512;
constexpr int TILE = 64;               // time steps per tile
constexpr int NTILE = T_ / TILE;       // 32 tiles
constexpr int NCHUNK = 64;             // neurons per block
constexpr int NPROD = 8;               // producer waves  (R3 had 4)
constexpr int RPP = TILE / NPROD;      // 8 rows per producer (exact)

__global__ __launch_bounds__(64 * (NPROD + 1), 1)
void exodus_pc8_kernel(const float* __restrict__ x,
                       const float* __restrict__ wptr,
                       float* __restrict__ out) {
    __shared__ float XBUF[2][TILE][NCHUNK];   // staged input tiles (32 KB)
    __shared__ float SBUF[2][TILE][NCHUNK];   // staged spike tiles (32 KB)

    const int blk  = blockIdx.x;          // 0..255
    const int b    = blk >> 3;            // 0..31
    const int n0   = (blk & 7) * NCHUNK;  // 0,64,...,448
    const int wave = threadIdx.x >> 6;    // 0..8
    const int lane = threadIdx.x & 63;

    const size_t base = (size_t)b * T_ * N_ + (size_t)n0 + lane;
    const float* __restrict__ xp = x + base;
    float* __restrict__ op = out + base;

    if (wave != 0) {
        // ================= producers =================
        const int p  = wave - 1;          // 0..7
        const int j0 = p * RPP;           // row range [j0, j0+8)

        // prologue: stage tile 0 (batched: 8 loads, then 8 ds_writes)
        {
            const float* __restrict__ g = xp + (size_t)j0 * N_;
            float r[RPP];
#pragma unroll
            for (int i = 0; i < RPP; ++i) r[i] = g[(size_t)i * N_];
#pragma unroll
            for (int i = 0; i < RPP; ++i) XBUF[0][j0 + i][lane] = r[i];
        }
        __syncthreads();

        for (int t = 0; t <= NTILE; ++t) {
            if (t + 1 < NTILE) {
                // prefetch tile t+1: 8 batched loads -> 8 ds_writes
                const float* __restrict__ g =
                    xp + ((size_t)(t + 1) * TILE + j0) * N_;
                const int bb = (t + 1) & 1;
                float r[RPP];
#pragma unroll
                for (int i = 0; i < RPP; ++i) r[i] = g[(size_t)i * N_];
#pragma unroll
                for (int i = 0; i < RPP; ++i) XBUF[bb][j0 + i][lane] = r[i];
            }
            if (t >= 1) {
                // drain spikes of tile t-1: 8 batched ds_reads -> 8 stores
                float* __restrict__ o =
                    op + ((size_t)(t - 1) * TILE + j0) * N_;
                const int bb = (t - 1) & 1;
                float s[RPP];
#pragma unroll
                for (int i = 0; i < RPP; ++i) s[i] = SBUF[bb][j0 + i][lane];
#pragma unroll
                for (int i = 0; i < RPP; ++i) o[(size_t)i * N_] = s[i];
            }
            __syncthreads();
        }
    } else {
        // ================= consumer =================
        const float w = wptr[0];
        const float alpha = (float)exp((double)(-1.0f / 20.0f));
        float vsyn = 0.0f, vmem = 0.0f;

        __syncthreads();   // matches producer prologue barrier

        for (int t = 0; t <= NTILE; ++t) {
            if (t < NTILE) {
                const int bb = t & 1;
#pragma unroll
                for (int c = 0; c < TILE / 32; ++c) {   // 2 chunks of 32
                    float xv[32];
#pragma unroll
                    for (int j = 0; j < 32; ++j)
                        xv[j] = XBUF[bb][c * 32 + j][lane];
#pragma unroll
                    for (int j = 0; j < 32; ++j) {
                        const float i_t = __fmul_rn(xv[j], w);
                        vsyn = __fadd_rn(__fmul_rn(alpha, vsyn), i_t);
                        const float va = __fadd_rn(__fmul_rn(alpha, vmem), vsyn);
                        const bool fire = (va >= 1.0f);
                        SBUF[bb][c * 32 + j][lane] = fire ? 1.0f : 0.0f;
                        vmem = fire ? __fsub_rn(va, 1.0f) : va;  // == va - spk
                    }
                }
            }
            __syncthreads();
        }
    }
}

extern "C" void kernel_launch(void* const* d_in, const int* in_sizes, int n_in,
                              void* d_out, int out_size, void* d_ws, size_t ws_size,
                              hipStream_t stream) {
    const float* x = (const float*)d_in[0];
    const float* w = (const float*)d_in[1];
    float* out = (float*)d_out;

    dim3 grid(256);               // one block per CU; 64 sequences per block
    dim3 block(64 * (NPROD + 1)); // 576 threads = 1 consumer + 8 producers
    hipLaunchKernelGGL(exodus_pc8_kernel, grid, block, 0, stream, x, w, out);
}